// Round 3
// baseline (752.020 us; speedup 1.0000x reference)
//
#include <hip/hip_runtime.h>
#include <hip/hip_fp16.h>
#include <math.h>

#define THREADS 256
#define NPB 512           // nodes per bin
#define SHIFT 9
#define MASK 511
#define MAX_BINS 256
#define CAPE 20480        // per-bin capacity (mu=16.3k, +8 sigma, +3*512 pad)
#define BIN_BLOCKS 512
#define SENT (-1)         // sentinel for pad slots (valid packed edges < 2^31)

#define MEGA_BLOCKS 256
#define MEGA_THREADS 1024

// ============================ grid barrier ===================================
// Hand-rolled device-scope barrier. Safe: grid=256 blocks, each needs <=64KB
// LDS and <=128 VGPR (enforced by 1024-thread launch bounds) -> every block is
// resident simultaneously on 256 CUs. Spin is bounded (~27ms) so a logic error
// fails loudly instead of hanging. __threadfence + agent-scope acq/rel handles
// cross-XCD L2 non-coherence (G16).
__device__ __forceinline__ void grid_bar(int* bar, int idx, int nb) {
    __syncthreads();
    __threadfence();   // release: make this block's stores device-visible
    if (threadIdx.x == 0) {
        __hip_atomic_fetch_add(&bar[idx], 1, __ATOMIC_ACQ_REL, __HIP_MEMORY_SCOPE_AGENT);
        for (int spin = 0; spin < (1 << 20); ++spin) {
            if (__hip_atomic_load(&bar[idx], __ATOMIC_ACQUIRE, __HIP_MEMORY_SCOPE_AGENT) >= nb) break;
            __builtin_amdgcn_s_sleep(1);
        }
    }
    __syncthreads();
    __threadfence();   // acquire side for all lanes
}

// ===================== MEGA: whole pipeline, one dispatch ====================
// Phase A = R19 k_bin (256 blocks), BAR, phase B = k_sort + fused xform1,
// BAR, phase C = gather1 (grid-stride), BAR, phase D = gather2.

__global__ void __launch_bounds__(1024) k_mega(
        const int* __restrict__ row, const int* __restrict__ col, int e,
        const float* __restrict__ x, const float* __restrict__ W1,
        const float* __restrict__ b1, const float* __restrict__ W2,
        const float* __restrict__ b2,
        int* __restrict__ binCnt, int* __restrict__ bar,
        int* __restrict__ binned, int* __restrict__ csr,
        int* __restrict__ gptr, int* __restrict__ gcnt,
        float* __restrict__ dinv, __half* __restrict__ z1h,
        __half2* __restrict__ z2h, float* __restrict__ out,
        int n, int nbins) {
    extern __shared__ int dyn[];     // phase A: sbuf2[per] ; phase B: cnt/scn/sW
    __shared__ int hist[MAX_BINS];
    __shared__ int cur[MAX_BINS];
    __shared__ int baseg[MAX_BINS];
    __shared__ int lofs[MAX_BINS];
    __shared__ int scnA[MAX_BINS];
    const int tid = threadIdx.x;
    const int bk  = blockIdx.x;

    // ---------------- phase A: bin edges by target>>9 ------------------------
    {
        int per = (((e + MEGA_BLOCKS - 1) / MEGA_BLOCKS) + 3) & ~3;
        int e0 = bk * per;
        int e1 = min(e0 + per, e);
        int cntL = max(0, e1 - e0);
        int* sbuf2 = dyn;
        if (tid < MAX_BINS) { hist[tid] = 0; cur[tid] = 0; }
        __syncthreads();
        int nq = cntL >> 2;
        const int4* r4 = (const int4*)(row + e0);
        const int4* c4 = (const int4*)(col + e0);
        // pass A: histogram from col
        for (int q = tid; q < nq; q += MEGA_THREADS) {
            int4 c = c4[q];
            atomicAdd(&hist[c.x >> SHIFT], 1);
            atomicAdd(&hist[c.y >> SHIFT], 1);
            atomicAdd(&hist[c.z >> SHIFT], 1);
            atomicAdd(&hist[c.w >> SHIFT], 1);
        }
        for (int li = (nq << 2) + tid; li < cntL; li += MEGA_THREADS)
            atomicAdd(&hist[col[e0 + li] >> SHIFT], 1);
        __syncthreads();
        if (tid < MAX_BINS) {
            int h = hist[tid];
            baseg[tid] = (h > 0) ? atomicAdd(&binCnt[tid], (h + 3) & ~3) : 0;  // x4 pad
            scnA[tid] = h;
        }
        __syncthreads();
        for (int off = 1; off < MAX_BINS; off <<= 1) {
            int a = (tid >= off && tid < MAX_BINS) ? scnA[tid - off] : 0;
            __syncthreads();
            if (tid < MAX_BINS) scnA[tid] += a;
            __syncthreads();
        }
        if (tid < MAX_BINS) lofs[tid] = scnA[tid] - hist[tid];
        __syncthreads();
        // pass B: re-read row+col, pack, scatter bin-contiguous into sbuf2
        for (int q = tid; q < nq; q += MEGA_THREADS) {
            int4 r = r4[q], c = c4[q];
            int b0 = c.x >> SHIFT, b1_ = c.y >> SHIFT, b2_ = c.z >> SHIFT, b3 = c.w >> SHIFT;
            int p0 = lofs[b0] + atomicAdd(&cur[b0], 1);
            sbuf2[p0] = (r.x << SHIFT) | (c.x & MASK);
            int p1 = lofs[b1_] + atomicAdd(&cur[b1_], 1);
            sbuf2[p1] = (r.y << SHIFT) | (c.y & MASK);
            int p2 = lofs[b2_] + atomicAdd(&cur[b2_], 1);
            sbuf2[p2] = (r.z << SHIFT) | (c.z & MASK);
            int p3 = lofs[b3] + atomicAdd(&cur[b3], 1);
            sbuf2[p3] = (r.w << SHIFT) | (c.w & MASK);
        }
        for (int li = (nq << 2) + tid; li < cntL; li += MEGA_THREADS) {
            int c = col[e0 + li], r = row[e0 + li], b = c >> SHIFT;
            int p = lofs[b] + atomicAdd(&cur[b], 1);
            sbuf2[p] = (r << SHIFT) | (c & MASK);
        }
        __syncthreads();
        // pass C: wave-per-bin flush, int4 chunks (baseg multiple of 4)
        int wv = tid >> 6, ln = tid & 63;
        for (int b = wv; b < MAX_BINS; b += 16) {
            int len = hist[b];
            if (len == 0) continue;
            int lo = lofs[b];
            int gb = baseg[b];
            int n4 = (len + 3) >> 2;
            for (int i4 = ln; i4 < n4; i4 += 64) {
                int base = i4 * 4;
                int4 v;
                v.x = (base + 0 < len) ? sbuf2[lo + base + 0] : SENT;
                v.y = (base + 1 < len) ? sbuf2[lo + base + 1] : SENT;
                v.z = (base + 2 < len) ? sbuf2[lo + base + 2] : SENT;
                v.w = (base + 3 < len) ? sbuf2[lo + base + 3] : SENT;
                int pos = gb + base;
                if (pos + 4 <= CAPE) *(int4*)(binned + b * CAPE + pos) = v;
            }
        }
    }
    grid_bar(bar, 0, (int)gridDim.x);

    // ---------------- phase B: per-bin counting sort + xform1 ----------------
    {
        int* cntB = dyn;                      // [NPB]
        int* scnB = dyn + NPB;                // [NPB]
        float* sW = (float*)(dyn + 2 * NPB);  // [400]
        int b = bk;
        if (b < nbins) {
            int t = tid;
            if (t < NPB) cntB[t] = 0;
            if (t < 25 * 16) sW[t] = W1[t];
            __syncthreads();
            int m = min(binCnt[b], CAPE);   // multiple of 4 (padded reservations)
            int m4 = m >> 2;
            const int4* eb4 = (const int4*)(binned + b * CAPE);
            const int4 S4 = make_int4(SENT, SENT, SENT, SENT);
            int4 q0 = (t        < m4) ? eb4[t]        : S4;
            int4 q1 = (t + 1024 < m4) ? eb4[t + 1024] : S4;
            int4 q2 = (t + 2048 < m4) ? eb4[t + 2048] : S4;
            int4 q3 = (t + 3072 < m4) ? eb4[t + 3072] : S4;
            int4 q4 = (t + 4096 < m4) ? eb4[t + 4096] : S4;
#define H4(q) { \
    if (q.x != SENT) atomicAdd(&cntB[q.x & MASK], 1); \
    if (q.y != SENT) atomicAdd(&cntB[q.y & MASK], 1); \
    if (q.z != SENT) atomicAdd(&cntB[q.z & MASK], 1); \
    if (q.w != SENT) atomicAdd(&cntB[q.w & MASK], 1); }
            H4(q0) H4(q1) H4(q2) H4(q3) H4(q4)
#undef H4
            __syncthreads();
            int v = 0, pv = 0;
            if (t < NPB) {
                v = cntB[t];
                pv = (v + 3) & ~3;  // 4-aligned degree for csr segment alignment
                scnB[t] = pv;
            }
            __syncthreads();
            for (int off = 1; off < NPB; off <<= 1) {
                int a = (t >= off && t < NPB) ? scnB[t - off] : 0;
                __syncthreads();
                if (t < NPB) scnB[t] += a;
                __syncthreads();
            }
            int node = b * NPB + t;
            float di = rsqrtf((float)(v + 1));
            if (t < NPB) {
                int excl = scnB[t] - pv;  // multiple of 4
                if (node < n) {
                    gptr[node] = b * CAPE + excl;
                    gcnt[node] = v;
                    dinv[node] = di;
                }
                cntB[t] = excl;  // reuse as cursor
            }
            __syncthreads();
#define P4(q) { \
    int ee, slot; \
    ee = q.x; if (ee != SENT) { slot = atomicAdd(&cntB[ee & MASK], 1); if (slot < CAPE) csr[b * CAPE + slot] = ee >> SHIFT; } \
    ee = q.y; if (ee != SENT) { slot = atomicAdd(&cntB[ee & MASK], 1); if (slot < CAPE) csr[b * CAPE + slot] = ee >> SHIFT; } \
    ee = q.z; if (ee != SENT) { slot = atomicAdd(&cntB[ee & MASK], 1); if (slot < CAPE) csr[b * CAPE + slot] = ee >> SHIFT; } \
    ee = q.w; if (ee != SENT) { slot = atomicAdd(&cntB[ee & MASK], 1); if (slot < CAPE) csr[b * CAPE + slot] = ee >> SHIFT; } }
            P4(q0) P4(q1) P4(q2) P4(q3) P4(q4)
#undef P4
            // fused layer-1 transform for this bin's nodes
            if (t < NPB && node < n) {
                const float* xr = x + (size_t)node * 25;
                float xi[25];
#pragma unroll
                for (int k = 0; k < 25; k++) xi[k] = xr[k];
                union { int4 q[2]; __half h[16]; } u;
#pragma unroll
                for (int c = 0; c < 16; c++) {
                    float a = 0.f;
#pragma unroll
                    for (int k = 0; k < 25; k++) a = fmaf(xi[k], sW[k * 16 + c], a);
                    u.h[c] = __float2half(a * di);
                }
                int4* o = (int4*)(z1h + (size_t)node * 16);
                o[0] = u.q[0];
                o[1] = u.q[1];
            }
        }
    }
    grid_bar(bar, 1, (int)gridDim.x);

    // ---------------- phase C: gather1 + bias/relu + @W2 ---------------------
    {
        const __half2* z1p = (const __half2*)z1h;
        int g = tid >> 3;       // 128 node-groups per block
        int c2 = tid & 7;
        for (int base = bk * 128; base < n; base += MEGA_BLOCKS * 128) {
            int node = base + g;
            if (node >= n) continue;
            int beg = gptr[node], d = gcnt[node];
            __half2 sv = z1p[(size_t)node * 8 + c2];
            float a0 = __low2float(sv), a1 = __high2float(sv);
            int e2 = 0;
            for (; e2 + 4 <= d; e2 += 4) {
                int4 s = *(const int4*)(csr + beg + e2);  // aligned
                __half2 v0 = z1p[(size_t)s.x * 8 + c2];
                __half2 v1 = z1p[(size_t)s.y * 8 + c2];
                __half2 v2 = z1p[(size_t)s.z * 8 + c2];
                __half2 v3 = z1p[(size_t)s.w * 8 + c2];
                a0 += (__low2float(v0) + __low2float(v1)) + (__low2float(v2) + __low2float(v3));
                a1 += (__high2float(v0) + __high2float(v1)) + (__high2float(v2) + __high2float(v3));
            }
            for (; e2 < d; e2++) {
                __half2 v = z1p[(size_t)csr[beg + e2] * 8 + c2];
                a0 += __low2float(v);
                a1 += __high2float(v);
            }
            float di = dinv[node];
            int cA = c2 * 2, cB = c2 * 2 + 1;
            float hA = fmaxf(fmaf(di, a0, b1[cA]), 0.f);
            float hB = fmaxf(fmaf(di, a1, b1[cB]), 0.f);
            float p0 = hA * W2[cA * 2 + 0] + hB * W2[cB * 2 + 0];
            float p1 = hA * W2[cA * 2 + 1] + hB * W2[cB * 2 + 1];
#pragma unroll
            for (int mm = 1; mm < 8; mm <<= 1) {
                p0 += __shfl_xor(p0, mm, 8);
                p1 += __shfl_xor(p1, mm, 8);
            }
            if (c2 == 0) z2h[node] = __floats2half2_rn(di * p0, di * p1);
        }
    }
    grid_bar(bar, 2, (int)gridDim.x);

    // ---------------- phase D: gather2 + bias + log_softmax ------------------
    {
        int g = tid >> 3;
        int c = tid & 7;
        for (int base = bk * 128; base < n; base += MEGA_BLOCKS * 128) {
            int node = base + g;
            if (node >= n) continue;
            int beg = gptr[node], d = gcnt[node];
            float a0 = 0.f, a1 = 0.f;
            for (int e2 = c; e2 < d; e2 += 8) {
                __half2 v = z2h[csr[beg + e2]];
                a0 += __low2float(v);
                a1 += __high2float(v);
            }
#pragma unroll
            for (int mm = 1; mm < 8; mm <<= 1) {
                a0 += __shfl_xor(a0, mm, 8);
                a1 += __shfl_xor(a1, mm, 8);
            }
            if (c == 0) {
                __half2 self = z2h[node];
                a0 += __low2float(self);
                a1 += __high2float(self);
                float di = dinv[node];
                float h0 = fmaf(di, a0, b2[0]);
                float h1 = fmaf(di, a1, b2[1]);
                float mx = fmaxf(h0, h1);
                float lse = mx + log1pf(expf(fminf(h0, h1) - mx));
                ((float2*)out)[node] = make_float2(h0 - lse, h1 - lse);
            }
        }
    }
}

// ===================== 4-kernel v17 path (mega fallback) =====================

__global__ void __launch_bounds__(512) k_bin(const int* __restrict__ row,
                                             const int* __restrict__ col,
                                             int e, int* __restrict__ binCnt,
                                             int* __restrict__ binned) {
    __shared__ int hist[MAX_BINS];
    __shared__ int cur[MAX_BINS];
    __shared__ int baseg[MAX_BINS];
    __shared__ int lofs[MAX_BINS];
    __shared__ int scn[MAX_BINS];
    extern __shared__ int sbuf2[];
    int per = (((e + (int)gridDim.x - 1) / (int)gridDim.x) + 3) & ~3;
    int e0 = blockIdx.x * per;
    if (e0 >= e) return;
    int e1 = min(e0 + per, e);
    int cntL = e1 - e0;
    int tid = threadIdx.x;
    if (tid < MAX_BINS) { hist[tid] = 0; cur[tid] = 0; }
    __syncthreads();
    int nq = cntL >> 2;
    const int4* r4 = (const int4*)(row + e0);
    const int4* c4 = (const int4*)(col + e0);
    for (int q = tid; q < nq; q += 512) {
        int4 c = c4[q];
        atomicAdd(&hist[c.x >> SHIFT], 1);
        atomicAdd(&hist[c.y >> SHIFT], 1);
        atomicAdd(&hist[c.z >> SHIFT], 1);
        atomicAdd(&hist[c.w >> SHIFT], 1);
    }
    for (int li = (nq << 2) + tid; li < cntL; li += 512) {
        atomicAdd(&hist[col[e0 + li] >> SHIFT], 1);
    }
    __syncthreads();
    if (tid < MAX_BINS) {
        int h = hist[tid];
        baseg[tid] = (h > 0) ? atomicAdd(&binCnt[tid], (h + 3) & ~3) : 0;
        scn[tid] = h;
    }
    __syncthreads();
    for (int off = 1; off < MAX_BINS; off <<= 1) {
        int a = (tid >= off && tid < MAX_BINS) ? scn[tid - off] : 0;
        __syncthreads();
        if (tid < MAX_BINS) scn[tid] += a;
        __syncthreads();
    }
    if (tid < MAX_BINS) lofs[tid] = scn[tid] - hist[tid];
    __syncthreads();
    for (int q = tid; q < nq; q += 512) {
        int4 r = r4[q], c = c4[q];
        int b0 = c.x >> SHIFT, b1 = c.y >> SHIFT, b2 = c.z >> SHIFT, b3 = c.w >> SHIFT;
        int p0 = lofs[b0] + atomicAdd(&cur[b0], 1);
        sbuf2[p0] = (r.x << SHIFT) | (c.x & MASK);
        int p1 = lofs[b1] + atomicAdd(&cur[b1], 1);
        sbuf2[p1] = (r.y << SHIFT) | (c.y & MASK);
        int p2 = lofs[b2] + atomicAdd(&cur[b2], 1);
        sbuf2[p2] = (r.z << SHIFT) | (c.z & MASK);
        int p3 = lofs[b3] + atomicAdd(&cur[b3], 1);
        sbuf2[p3] = (r.w << SHIFT) | (c.w & MASK);
    }
    for (int li = (nq << 2) + tid; li < cntL; li += 512) {
        int c = col[e0 + li], r = row[e0 + li], b = c >> SHIFT;
        int p = lofs[b] + atomicAdd(&cur[b], 1);
        sbuf2[p] = (r << SHIFT) | (c & MASK);
    }
    __syncthreads();
    int wv = tid >> 6, ln = tid & 63;
    for (int b = wv; b < MAX_BINS; b += 8) {
        int len = hist[b];
        if (len == 0) continue;
        int lo = lofs[b];
        int gb = baseg[b];
        int n4 = (len + 3) >> 2;
        for (int i4 = ln; i4 < n4; i4 += 64) {
            int base = i4 * 4;
            int4 v;
            v.x = (base + 0 < len) ? sbuf2[lo + base + 0] : SENT;
            v.y = (base + 1 < len) ? sbuf2[lo + base + 1] : SENT;
            v.z = (base + 2 < len) ? sbuf2[lo + base + 2] : SENT;
            v.w = (base + 3 < len) ? sbuf2[lo + base + 3] : SENT;
            int pos = gb + base;
            if (pos + 4 <= CAPE) *(int4*)(binned + b * CAPE + pos) = v;
        }
    }
}

__global__ void __launch_bounds__(1024) k_sort(const int* __restrict__ binned,
                                               const int* __restrict__ binCnt,
                                               int* __restrict__ csr,
                                               int* __restrict__ gptr,
                                               int* __restrict__ gcnt,
                                               float* __restrict__ dinv,
                                               const float* __restrict__ x,
                                               const float* __restrict__ W1,
                                               __half* __restrict__ z1h, int n) {
    __shared__ int cnt[NPB];
    __shared__ int scn[NPB];
    __shared__ float sW[25 * 16];
    int b = blockIdx.x;
    int t = threadIdx.x;
    if (t < NPB) cnt[t] = 0;
    if (t < 25 * 16) sW[t] = W1[t];
    __syncthreads();
    int m = min(binCnt[b], CAPE);
    int m4 = m >> 2;
    const int4* eb4 = (const int4*)(binned + b * CAPE);
    const int4 S4 = make_int4(SENT, SENT, SENT, SENT);
    int4 q0 = (t        < m4) ? eb4[t]        : S4;
    int4 q1 = (t + 1024 < m4) ? eb4[t + 1024] : S4;
    int4 q2 = (t + 2048 < m4) ? eb4[t + 2048] : S4;
    int4 q3 = (t + 3072 < m4) ? eb4[t + 3072] : S4;
    int4 q4 = (t + 4096 < m4) ? eb4[t + 4096] : S4;
#define H4(q) { \
    if (q.x != SENT) atomicAdd(&cnt[q.x & MASK], 1); \
    if (q.y != SENT) atomicAdd(&cnt[q.y & MASK], 1); \
    if (q.z != SENT) atomicAdd(&cnt[q.z & MASK], 1); \
    if (q.w != SENT) atomicAdd(&cnt[q.w & MASK], 1); }
    H4(q0) H4(q1) H4(q2) H4(q3) H4(q4)
#undef H4
    __syncthreads();
    int v = 0, pv = 0;
    if (t < NPB) {
        v = cnt[t];
        pv = (v + 3) & ~3;
        scn[t] = pv;
    }
    __syncthreads();
    for (int off = 1; off < NPB; off <<= 1) {
        int a = (t >= off && t < NPB) ? scn[t - off] : 0;
        __syncthreads();
        if (t < NPB) scn[t] += a;
        __syncthreads();
    }
    int node = b * NPB + t;
    float di = rsqrtf((float)(v + 1));
    if (t < NPB) {
        int excl = scn[t] - pv;
        if (node < n) {
            gptr[node] = b * CAPE + excl;
            gcnt[node] = v;
            dinv[node] = di;
        }
        cnt[t] = excl;
    }
    __syncthreads();
#define P4(q) { \
    int e, slot; \
    e = q.x; if (e != SENT) { slot = atomicAdd(&cnt[e & MASK], 1); if (slot < CAPE) csr[b * CAPE + slot] = e >> SHIFT; } \
    e = q.y; if (e != SENT) { slot = atomicAdd(&cnt[e & MASK], 1); if (slot < CAPE) csr[b * CAPE + slot] = e >> SHIFT; } \
    e = q.z; if (e != SENT) { slot = atomicAdd(&cnt[e & MASK], 1); if (slot < CAPE) csr[b * CAPE + slot] = e >> SHIFT; } \
    e = q.w; if (e != SENT) { slot = atomicAdd(&cnt[e & MASK], 1); if (slot < CAPE) csr[b * CAPE + slot] = e >> SHIFT; } }
    P4(q0) P4(q1) P4(q2) P4(q3) P4(q4)
#undef P4
    if (t < NPB && node < n) {
        const float* xr = x + (size_t)node * 25;
        float xi[25];
#pragma unroll
        for (int k = 0; k < 25; k++) xi[k] = xr[k];
        union { int4 q[2]; __half h[16]; } u;
#pragma unroll
        for (int c = 0; c < 16; c++) {
            float a = 0.f;
#pragma unroll
            for (int k = 0; k < 25; k++) a = fmaf(xi[k], sW[k * 16 + c], a);
            u.h[c] = __float2half(a * di);
        }
        int4* o = (int4*)(z1h + (size_t)node * 16);
        o[0] = u.q[0];
        o[1] = u.q[1];
    }
}

__global__ void __launch_bounds__(256) k_xform1(const float* __restrict__ x,
                                                const float* __restrict__ W1,
                                                const float* __restrict__ dinv,
                                                __half* __restrict__ z1h, int n) {
    __shared__ float sW[25 * 16];
    for (int t = threadIdx.x; t < 25 * 16; t += 256) sW[t] = W1[t];
    __syncthreads();
    long node = (long)blockIdx.x * 256 + threadIdx.x;
    if (node >= n) return;
    const float* xr = x + node * 25;
    float xi[25];
#pragma unroll
    for (int k = 0; k < 25; k++) xi[k] = xr[k];
    float di = dinv[node];
    union { int4 q[2]; __half h[16]; } u;
#pragma unroll
    for (int c = 0; c < 16; c++) {
        float a = 0.f;
#pragma unroll
        for (int k = 0; k < 25; k++) a = fmaf(xi[k], sW[k * 16 + c], a);
        u.h[c] = __float2half(a * di);
    }
    int4* o = (int4*)(z1h + node * 16);
    o[0] = u.q[0];
    o[1] = u.q[1];
}

__global__ void k_gather1(const int* __restrict__ ptr, const int* __restrict__ cnt,
                          const int* __restrict__ csr, const __half* __restrict__ z1h,
                          const float* __restrict__ dinv,
                          const float* __restrict__ b1, const float* __restrict__ W2,
                          __half2* __restrict__ z2h, int n) {
    int g = threadIdx.x >> 3;
    int c2 = threadIdx.x & 7;
    int node = blockIdx.x * 32 + g;
    if (node >= n) return;
    const __half2* z1p = (const __half2*)z1h;
    int beg = ptr[node], d = cnt[node];
    __half2 sv = z1p[(size_t)node * 8 + c2];
    float a0 = __low2float(sv), a1 = __high2float(sv);
    int e = 0;
    for (; e + 4 <= d; e += 4) {
        int4 s = *(const int4*)(csr + beg + e);
        __half2 v0 = z1p[(size_t)s.x * 8 + c2];
        __half2 v1 = z1p[(size_t)s.y * 8 + c2];
        __half2 v2 = z1p[(size_t)s.z * 8 + c2];
        __half2 v3 = z1p[(size_t)s.w * 8 + c2];
        a0 += (__low2float(v0) + __low2float(v1)) + (__low2float(v2) + __low2float(v3));
        a1 += (__high2float(v0) + __high2float(v1)) + (__high2float(v2) + __high2float(v3));
    }
    for (; e < d; e++) {
        __half2 v = z1p[(size_t)csr[beg + e] * 8 + c2];
        a0 += __low2float(v);
        a1 += __high2float(v);
    }
    float di = dinv[node];
    int cA = c2 * 2, cB = c2 * 2 + 1;
    float hA = fmaxf(fmaf(di, a0, b1[cA]), 0.f);
    float hB = fmaxf(fmaf(di, a1, b1[cB]), 0.f);
    float p0 = hA * W2[cA * 2 + 0] + hB * W2[cB * 2 + 0];
    float p1 = hA * W2[cA * 2 + 1] + hB * W2[cB * 2 + 1];
#pragma unroll
    for (int m = 1; m < 8; m <<= 1) {
        p0 += __shfl_xor(p0, m, 8);
        p1 += __shfl_xor(p1, m, 8);
    }
    if (c2 == 0) z2h[node] = __floats2half2_rn(di * p0, di * p1);
}

__global__ void k_gather2(const int* __restrict__ ptr, const int* __restrict__ cnt,
                          const int* __restrict__ csr, const __half2* __restrict__ z2h,
                          const float* __restrict__ dinv,
                          const float* __restrict__ b2, float* __restrict__ out, int n) {
    int g = threadIdx.x >> 3;
    int c = threadIdx.x & 7;
    int node = blockIdx.x * 32 + g;
    if (node >= n) return;
    int beg = ptr[node], d = cnt[node];
    float a0 = 0.f, a1 = 0.f;
    for (int e = c; e < d; e += 8) {
        __half2 v = z2h[csr[beg + e]];
        a0 += __low2float(v);
        a1 += __high2float(v);
    }
#pragma unroll
    for (int m = 1; m < 8; m <<= 1) {
        a0 += __shfl_xor(a0, m, 8);
        a1 += __shfl_xor(a1, m, 8);
    }
    if (c == 0) {
        __half2 self = z2h[node];
        a0 += __low2float(self);
        a1 += __high2float(self);
        float di = dinv[node];
        float h0 = fmaf(di, a0, b2[0]);
        float h1 = fmaf(di, a1, b2[1]);
        float mx = fmaxf(h0, h1);
        float lse = mx + log1pf(expf(fminf(h0, h1) - mx));
        ((float2*)out)[node] = make_float2(h0 - lse, h1 - lse);
    }
}

// ===================== fallback: round-2 CSR pipeline ========================

__global__ void k_zero(int* cnt, int n) {
    int i = blockIdx.x * blockDim.x + threadIdx.x;
    if (i < n) cnt[i] = 0;
}

__global__ void k_count_pos(const int* __restrict__ col, int e,
                            int* __restrict__ cnt, int* __restrict__ pos) {
    int i = blockIdx.x * blockDim.x + threadIdx.x;
    if (i < e) pos[i] = atomicAdd(&cnt[col[i]], 1);
}

__global__ void k_scan1(const int* __restrict__ cnt, int n,
                        int* __restrict__ excl, int* __restrict__ bsum) {
    __shared__ int s[256];
    int i = blockIdx.x * 256 + threadIdx.x;
    int v = (i < n) ? cnt[i] : 0;
    s[threadIdx.x] = v;
    __syncthreads();
    for (int off = 1; off < 256; off <<= 1) {
        int t = (threadIdx.x >= off) ? s[threadIdx.x - off] : 0;
        __syncthreads();
        s[threadIdx.x] += t;
        __syncthreads();
    }
    if (i < n) excl[i] = s[threadIdx.x] - v;
    if (threadIdx.x == 255) bsum[blockIdx.x] = s[255];
}

__global__ void k_scan2(int* __restrict__ bsum, int nb) {
    __shared__ int s[1024];
    int v = (threadIdx.x < nb) ? bsum[threadIdx.x] : 0;
    s[threadIdx.x] = v;
    __syncthreads();
    for (int off = 1; off < 1024; off <<= 1) {
        int t = (threadIdx.x >= off) ? s[threadIdx.x - off] : 0;
        __syncthreads();
        s[threadIdx.x] += t;
        __syncthreads();
    }
    if (threadIdx.x < nb) bsum[threadIdx.x] = s[threadIdx.x] - v;
}

__global__ void k_scan3(int* __restrict__ excl, const int* __restrict__ boff, int n) {
    int i = blockIdx.x * 256 + threadIdx.x;
    if (i < n) excl[i] += boff[blockIdx.x];
}

__global__ void k_place(const int* __restrict__ row, const int* __restrict__ col,
                        const int* __restrict__ pos, const int* __restrict__ ptr,
                        int e, int* __restrict__ csr) {
    int i = blockIdx.x * blockDim.x + threadIdx.x;
    if (i >= e) return;
    csr[ptr[col[i]] + pos[i]] = row[i];
}

__global__ void k_dinv_from_cnt(const int* __restrict__ cnt, float* __restrict__ dinv, int n) {
    int i = blockIdx.x * blockDim.x + threadIdx.x;
    if (i < n) dinv[i] = rsqrtf((float)(cnt[i] + 1));
}

__global__ void k_gather1_fb(const int* __restrict__ ptr, const int* __restrict__ cnt,
                             const int* __restrict__ csr, const __half* __restrict__ z1h,
                             const float* __restrict__ dinv,
                             const float* __restrict__ b1, const float* __restrict__ W2,
                             __half2* __restrict__ z2h, int n) {
    int g = threadIdx.x >> 3;
    int c2 = threadIdx.x & 7;
    int node = blockIdx.x * 32 + g;
    if (node >= n) return;
    const __half2* z1p = (const __half2*)z1h;
    int beg = ptr[node], d = cnt[node];
    __half2 sv = z1p[(size_t)node * 8 + c2];
    float a0 = __low2float(sv), a1 = __high2float(sv);
    for (int e = 0; e < d; e++) {
        __half2 v = z1p[(size_t)csr[beg + e] * 8 + c2];
        a0 += __low2float(v);
        a1 += __high2float(v);
    }
    float di = dinv[node];
    int cA = c2 * 2, cB = c2 * 2 + 1;
    float hA = fmaxf(fmaf(di, a0, b1[cA]), 0.f);
    float hB = fmaxf(fmaf(di, a1, b1[cB]), 0.f);
    float p0 = hA * W2[cA * 2 + 0] + hB * W2[cB * 2 + 0];
    float p1 = hA * W2[cA * 2 + 1] + hB * W2[cB * 2 + 1];
#pragma unroll
    for (int m = 1; m < 8; m <<= 1) {
        p0 += __shfl_xor(p0, m, 8);
        p1 += __shfl_xor(p1, m, 8);
    }
    if (c2 == 0) z2h[node] = __floats2half2_rn(di * p0, di * p1);
}

// ============================== host launcher ================================

extern "C" void kernel_launch(void* const* d_in, const int* in_sizes, int n_in,
                              void* d_out, int out_size, void* d_ws, size_t ws_size,
                              hipStream_t stream) {
    const float* x  = (const float*)d_in[0];
    const int*   ei = (const int*)d_in[1];
    const float* W1 = (const float*)d_in[2];
    const float* b1 = (const float*)d_in[3];
    const float* W2 = (const float*)d_in[4];
    const float* b2 = (const float*)d_in[5];
    float* out = (float*)d_out;

    const int N = in_sizes[0] / 25;
    const int E = in_sizes[1] / 2;
    const int* row = ei;
    const int* col = ei + E;

    const int nbins = (N + NPB - 1) / NPB;
    const int gN = (N + THREADS - 1) / THREADS;
    const int gE = (E + THREADS - 1) / THREADS;

    size_t off = 0;
    auto take = [&](size_t bytes) { size_t o = off; off = (off + bytes + 255) & ~(size_t)255; return o; };
    size_t o_binCnt = take((MAX_BINS + 8) * sizeof(int));  // binCnt + barrier slots
    size_t o_binned = take((size_t)nbins * CAPE * sizeof(int));
    size_t o_csr    = take((size_t)nbins * CAPE * sizeof(int));
    size_t o_ptr    = take((size_t)N * sizeof(int));
    size_t o_cnt    = take((size_t)N * sizeof(int));
    size_t o_dinv   = take((size_t)N * sizeof(float));
    size_t o_z1h    = take((size_t)N * 16 * sizeof(__half));
    size_t o_z2h    = take((size_t)N * sizeof(__half2));
    size_t need_v17 = off;

    double mu = (double)E / (double)nbins;
    bool cap_ok = (mu + 8.0 * sqrt(mu) + 3.0 * NPB) < (double)CAPE;

    // mega path: 256 blocks x 1024 threads, single dispatch with grid barriers
    const int perM = (((E + MEGA_BLOCKS - 1) / MEGA_BLOCKS) + 3) & ~3;
    size_t dynA = (size_t)perM * 4;                       // phase-A sbuf2
    size_t dynB = (size_t)(2 * NPB + 25 * 16) * 4;        // phase-B cnt/scn/sW
    size_t dynM = ((dynA > dynB ? dynA : dynB) + 63) & ~(size_t)63;
    bool mega_ok = (nbins <= MAX_BINS) && (ws_size >= need_v17) &&
                   (N <= NPB * MAX_BINS) && cap_ok && (dynM <= 59 * 1024);

    // v17 4-kernel path constraints
    const int per = (((E + BIN_BLOCKS - 1) / BIN_BLOCKS) + 3) & ~3;
    size_t dynLds = (size_t)per * 4 + 64;
    bool lds_ok = dynLds <= 60 * 1024;
    bool use_v17 = (nbins <= MAX_BINS) && (ws_size >= need_v17) &&
                   (N <= NPB * MAX_BINS) && cap_ok && lds_ok;

    char* wsb = (char*)d_ws;
    if (mega_ok) {
        int*     binCnt = (int*)(wsb + o_binCnt);
        int*     bar    = binCnt + MAX_BINS;
        int*     binned = (int*)(wsb + o_binned);
        int*     csr    = (int*)(wsb + o_csr);
        int*     ptr    = (int*)(wsb + o_ptr);
        int*     cnt    = (int*)(wsb + o_cnt);
        float*   dinv   = (float*)(wsb + o_dinv);
        __half*  z1h    = (__half*)(wsb + o_z1h);
        __half2* z2h    = (__half2*)(wsb + o_z2h);

        hipMemsetAsync(binCnt, 0, (MAX_BINS + 8) * sizeof(int), stream);
        k_mega<<<MEGA_BLOCKS, MEGA_THREADS, dynM, stream>>>(
            row, col, E, x, W1, b1, W2, b2,
            binCnt, bar, binned, csr, ptr, cnt, dinv, z1h, z2h, out, N, nbins);
    } else if (use_v17) {
        int*     binCnt = (int*)(wsb + o_binCnt);
        int*     binned = (int*)(wsb + o_binned);
        int*     csr    = (int*)(wsb + o_csr);
        int*     ptr    = (int*)(wsb + o_ptr);
        int*     cnt    = (int*)(wsb + o_cnt);
        float*   dinv   = (float*)(wsb + o_dinv);
        __half*  z1h    = (__half*)(wsb + o_z1h);
        __half2* z2h    = (__half2*)(wsb + o_z2h);

        hipMemsetAsync(binCnt, 0, MAX_BINS * sizeof(int), stream);
        k_bin<<<BIN_BLOCKS, 512, dynLds, stream>>>(row, col, E, binCnt, binned);
        k_sort<<<nbins, 1024, 0, stream>>>(binned, binCnt, csr, ptr, cnt, dinv, x, W1, z1h, N);
        k_gather1<<<(N + 31) / 32, 256, 0, stream>>>(ptr, cnt, csr, z1h, dinv, b1, W2, z2h, N);
        k_gather2<<<(N + 31) / 32, 256, 0, stream>>>(ptr, cnt, csr, z2h, dinv, b2, out, N);
    } else {
        char* w = wsb;
        int*     cnt  = (int*)w;     w += (size_t)N * sizeof(int);
        int*     ptr  = (int*)w;     w += (size_t)N * sizeof(int);
        int*     pos  = (int*)w;     w += (size_t)E * sizeof(int);
        int*     csr  = (int*)w;     w += (size_t)E * sizeof(int);
        int*     bsum = (int*)w;     w += (size_t)1024 * sizeof(int);
        float*   dinv = (float*)w;   w += (size_t)N * sizeof(float);
        __half*  z1h  = (__half*)w;  w += (size_t)N * 16 * sizeof(__half);
        __half2* z2h  = (__half2*)w; w += (size_t)N * sizeof(__half2);
        const int NB = (N + 255) / 256;

        k_zero<<<gN, THREADS, 0, stream>>>(cnt, N);
        k_count_pos<<<gE, THREADS, 0, stream>>>(col, E, cnt, pos);
        k_scan1<<<NB, 256, 0, stream>>>(cnt, N, ptr, bsum);
        k_scan2<<<1, 1024, 0, stream>>>(bsum, NB);
        k_scan3<<<NB, 256, 0, stream>>>(ptr, bsum, N);
        k_place<<<gE, THREADS, 0, stream>>>(row, col, pos, ptr, E, csr);
        k_dinv_from_cnt<<<gN, THREADS, 0, stream>>>(cnt, dinv, N);
        k_xform1<<<gN, 256, 0, stream>>>(x, W1, dinv, z1h, N);
        k_gather1_fb<<<(N + 31) / 32, 256, 0, stream>>>(ptr, cnt, csr, z1h, dinv, b1, W2, z2h, N);
        k_gather2<<<(N + 31) / 32, 256, 0, stream>>>(ptr, cnt, csr, z2h, dinv, b2, out, N);
    }
}

// Round 7
// 179.550 us; speedup vs baseline: 4.1884x; 4.1884x over previous
//
#include <hip/hip_runtime.h>
#include <hip/hip_fp16.h>
#include <math.h>

#define THREADS 256
#define NPB 512           // nodes per bin
#define SHIFT 9
#define MASK 511
#define MAX_BINS 256
#define CAPE 20480        // per-bin capacity (true mean 16384, +8 sigma, +3*512 pad)
#define BIN_BLOCKS 512
#define SENT (-1)         // sentinel for pad slots (valid packed edges < 2^31)

// ===================== stage 1: bin edges by target>>9 =======================
// R17: reservations padded to x4 (16B-aligned bases), pass C flushes int4
// chunks with SENT in pad slots.
// R19: dropped sbuf/sbin staging (dynLDS 56KB -> 25KB => 4 blocks/CU = 32
// waves, was 2 blocks/16 waves). Pass A histograms from col directly; pass B
// re-reads row/col (coalesced, L2-warm) and packs+scatters into sbuf2.
// R25: byte-exact revert to the R19 kernel (verified 178.6us). R22's
// BIN_BLOCKS=1024 variant hit repeated opaque container failures AND had
// zero capacity margin (16384 + 8sigma + 3*1024 == CAPE exactly).

__global__ void __launch_bounds__(512) k_bin(const int* __restrict__ row,
                                             const int* __restrict__ col,
                                             int e, int* __restrict__ binCnt,
                                             int* __restrict__ binned) {
    __shared__ int hist[MAX_BINS];
    __shared__ int cur[MAX_BINS];
    __shared__ int baseg[MAX_BINS];
    __shared__ int lofs[MAX_BINS];
    __shared__ int scn[MAX_BINS];
    extern __shared__ int sbuf2[];   // per ints
    int per = (((e + (int)gridDim.x - 1) / (int)gridDim.x) + 3) & ~3;
    int e0 = blockIdx.x * per;
    if (e0 >= e) return;
    int e1 = min(e0 + per, e);
    int cntL = e1 - e0;
    int tid = threadIdx.x;
    if (tid < MAX_BINS) { hist[tid] = 0; cur[tid] = 0; }
    __syncthreads();
    int nq = cntL >> 2;
    const int4* r4 = (const int4*)(row + e0);
    const int4* c4 = (const int4*)(col + e0);
    // pass A: histogram only (col read, 4 LDS atomics per int4)
    for (int q = tid; q < nq; q += 512) {
        int4 c = c4[q];
        atomicAdd(&hist[c.x >> SHIFT], 1);
        atomicAdd(&hist[c.y >> SHIFT], 1);
        atomicAdd(&hist[c.z >> SHIFT], 1);
        atomicAdd(&hist[c.w >> SHIFT], 1);
    }
    for (int li = (nq << 2) + tid; li < cntL; li += 512) {
        atomicAdd(&hist[col[e0 + li] >> SHIFT], 1);
    }
    __syncthreads();
    if (tid < MAX_BINS) {
        int h = hist[tid];
        baseg[tid] = (h > 0) ? atomicAdd(&binCnt[tid], (h + 3) & ~3) : 0;  // x4 pad
        scn[tid] = h;
    }
    __syncthreads();
    for (int off = 1; off < MAX_BINS; off <<= 1) {
        int a = (tid >= off && tid < MAX_BINS) ? scn[tid - off] : 0;
        __syncthreads();
        if (tid < MAX_BINS) scn[tid] += a;
        __syncthreads();
    }
    if (tid < MAX_BINS) lofs[tid] = scn[tid] - hist[tid];
    __syncthreads();
    // pass B: re-read row+col, pack, scatter bin-contiguous into sbuf2
    for (int q = tid; q < nq; q += 512) {
        int4 r = r4[q], c = c4[q];
        int b0 = c.x >> SHIFT, b1 = c.y >> SHIFT, b2 = c.z >> SHIFT, b3 = c.w >> SHIFT;
        int p0 = lofs[b0] + atomicAdd(&cur[b0], 1);
        sbuf2[p0] = (r.x << SHIFT) | (c.x & MASK);
        int p1 = lofs[b1] + atomicAdd(&cur[b1], 1);
        sbuf2[p1] = (r.y << SHIFT) | (c.y & MASK);
        int p2 = lofs[b2] + atomicAdd(&cur[b2], 1);
        sbuf2[p2] = (r.z << SHIFT) | (c.z & MASK);
        int p3 = lofs[b3] + atomicAdd(&cur[b3], 1);
        sbuf2[p3] = (r.w << SHIFT) | (c.w & MASK);
    }
    for (int li = (nq << 2) + tid; li < cntL; li += 512) {
        int c = col[e0 + li], r = row[e0 + li], b = c >> SHIFT;
        int p = lofs[b] + atomicAdd(&cur[b], 1);
        sbuf2[p] = (r << SHIFT) | (c & MASK);
    }
    __syncthreads();
    // pass C: wave-per-bin flush, int4 chunks (baseg multiple of 4)
    int wv = tid >> 6, ln = tid & 63;
    for (int b = wv; b < MAX_BINS; b += 8) {
        int len = hist[b];
        if (len == 0) continue;
        int lo = lofs[b];
        int gb = baseg[b];
        int n4 = (len + 3) >> 2;
        for (int i4 = ln; i4 < n4; i4 += 64) {
            int base = i4 * 4;
            int4 v;
            v.x = (base + 0 < len) ? sbuf2[lo + base + 0] : SENT;
            v.y = (base + 1 < len) ? sbuf2[lo + base + 1] : SENT;
            v.z = (base + 2 < len) ? sbuf2[lo + base + 2] : SENT;
            v.w = (base + 3 < len) ? sbuf2[lo + base + 3] : SENT;
            int pos = gb + base;
            if (pos + 4 <= CAPE) *(int4*)(binned + b * CAPE + pos) = v;
        }
    }
}

// ======= stage 2 (FUSED): per-bin counting sort -> CSR + deg + dinv ==========
// + layer-1 transform. R19: binned is read ONCE into 5 statically-indexed
// int4 registers per thread (m4 <= CAPE/4 = 5120 = 5*1024); both the
// histogram and placement passes run from registers — removes the second
// 12.8MB global pass and all load-latency from the placement pass.

__global__ void __launch_bounds__(1024) k_sort(const int* __restrict__ binned,
                                               const int* __restrict__ binCnt,
                                               int* __restrict__ csr,
                                               int* __restrict__ gptr,
                                               int* __restrict__ gcnt,
                                               float* __restrict__ dinv,
                                               const float* __restrict__ x,
                                               const float* __restrict__ W1,
                                               __half* __restrict__ z1h, int n) {
    __shared__ int cnt[NPB];
    __shared__ int scn[NPB];
    __shared__ float sW[25 * 16];
    int b = blockIdx.x;
    int t = threadIdx.x;
    if (t < NPB) cnt[t] = 0;
    if (t < 25 * 16) sW[t] = W1[t];
    __syncthreads();
    int m = min(binCnt[b], CAPE);   // multiple of 4 (padded reservations)
    int m4 = m >> 2;
    const int4* eb4 = (const int4*)(binned + b * CAPE);
    const int4 S4 = make_int4(SENT, SENT, SENT, SENT);
    int4 q0 = (t          < m4) ? eb4[t]          : S4;
    int4 q1 = (t + 1024   < m4) ? eb4[t + 1024]   : S4;
    int4 q2 = (t + 2048   < m4) ? eb4[t + 2048]   : S4;
    int4 q3 = (t + 3072   < m4) ? eb4[t + 3072]   : S4;
    int4 q4 = (t + 4096   < m4) ? eb4[t + 4096]   : S4;
#define H4(q) { \
    if (q.x != SENT) atomicAdd(&cnt[q.x & MASK], 1); \
    if (q.y != SENT) atomicAdd(&cnt[q.y & MASK], 1); \
    if (q.z != SENT) atomicAdd(&cnt[q.z & MASK], 1); \
    if (q.w != SENT) atomicAdd(&cnt[q.w & MASK], 1); }
    H4(q0) H4(q1) H4(q2) H4(q3) H4(q4)
#undef H4
    __syncthreads();
    int v = 0, pv = 0;
    if (t < NPB) {
        v = cnt[t];
        pv = (v + 3) & ~3;  // 4-aligned degree for csr segment alignment
        scn[t] = pv;
    }
    __syncthreads();
    for (int off = 1; off < NPB; off <<= 1) {
        int a = (t >= off && t < NPB) ? scn[t - off] : 0;
        __syncthreads();
        if (t < NPB) scn[t] += a;
        __syncthreads();
    }
    int node = b * NPB + t;
    float di = rsqrtf((float)(v + 1));
    if (t < NPB) {
        int excl = scn[t] - pv;  // multiple of 4
        if (node < n) {
            gptr[node] = b * CAPE + excl;
            gcnt[node] = v;
            dinv[node] = di;
        }
        cnt[t] = excl;  // reuse as cursor
    }
    __syncthreads();
#define P4(q) { \
    int e, slot; \
    e = q.x; if (e != SENT) { slot = atomicAdd(&cnt[e & MASK], 1); if (slot < CAPE) csr[b * CAPE + slot] = e >> SHIFT; } \
    e = q.y; if (e != SENT) { slot = atomicAdd(&cnt[e & MASK], 1); if (slot < CAPE) csr[b * CAPE + slot] = e >> SHIFT; } \
    e = q.z; if (e != SENT) { slot = atomicAdd(&cnt[e & MASK], 1); if (slot < CAPE) csr[b * CAPE + slot] = e >> SHIFT; } \
    e = q.w; if (e != SENT) { slot = atomicAdd(&cnt[e & MASK], 1); if (slot < CAPE) csr[b * CAPE + slot] = e >> SHIFT; } }
    P4(q0) P4(q1) P4(q2) P4(q3) P4(q4)
#undef P4
    // fused layer-1 transform for this bin's nodes
    if (t < NPB && node < n) {
        const float* xr = x + (size_t)node * 25;
        float xi[25];
#pragma unroll
        for (int k = 0; k < 25; k++) xi[k] = xr[k];
        union { int4 q[2]; __half h[16]; } u;
#pragma unroll
        for (int c = 0; c < 16; c++) {
            float a = 0.f;
#pragma unroll
            for (int k = 0; k < 25; k++) a = fmaf(xi[k], sW[k * 16 + c], a);
            u.h[c] = __float2half(a * di);
        }
        int4* o = (int4*)(z1h + (size_t)node * 16);
        o[0] = u.q[0];
        o[1] = u.q[1];
    }
}

// --- standalone xform1 (fallback path only) ----------------------------------
__global__ void __launch_bounds__(256) k_xform1(const float* __restrict__ x,
                                                const float* __restrict__ W1,
                                                const float* __restrict__ dinv,
                                                __half* __restrict__ z1h, int n) {
    __shared__ float sW[25 * 16];
    for (int t = threadIdx.x; t < 25 * 16; t += 256) sW[t] = W1[t];
    __syncthreads();
    long node = (long)blockIdx.x * 256 + threadIdx.x;
    if (node >= n) return;
    const float* xr = x + node * 25;
    float xi[25];
#pragma unroll
    for (int k = 0; k < 25; k++) xi[k] = xr[k];
    float di = dinv[node];
    union { int4 q[2]; __half h[16]; } u;
#pragma unroll
    for (int c = 0; c < 16; c++) {
        float a = 0.f;
#pragma unroll
        for (int k = 0; k < 25; k++) a = fmaf(xi[k], sW[k * 16 + c], a);
        u.h[c] = __float2half(a * di);
    }
    int4* o = (int4*)(z1h + node * 16);
    o[0] = u.q[0];
    o[1] = u.q[1];
}

// --- gather layer 1 + bias/relu + @W2: 8 lanes/node, half2 loads, ------------
// int4 csr loads (csr segments 16B-aligned by k_sort's padded scan).
__global__ void k_gather1(const int* __restrict__ ptr, const int* __restrict__ cnt,
                          const int* __restrict__ csr, const __half* __restrict__ z1h,
                          const float* __restrict__ dinv,
                          const float* __restrict__ b1, const float* __restrict__ W2,
                          __half2* __restrict__ z2h, int n) {
    int g = threadIdx.x >> 3;
    int c2 = threadIdx.x & 7;
    int node = blockIdx.x * 32 + g;
    if (node >= n) return;
    const __half2* z1p = (const __half2*)z1h;
    int beg = ptr[node], d = cnt[node];
    __half2 sv = z1p[(size_t)node * 8 + c2];
    float a0 = __low2float(sv), a1 = __high2float(sv);
    int e = 0;
    for (; e + 4 <= d; e += 4) {
        int4 s = *(const int4*)(csr + beg + e);  // aligned: beg%4==0, e%4==0
        __half2 v0 = z1p[(size_t)s.x * 8 + c2];
        __half2 v1 = z1p[(size_t)s.y * 8 + c2];
        __half2 v2 = z1p[(size_t)s.z * 8 + c2];
        __half2 v3 = z1p[(size_t)s.w * 8 + c2];
        a0 += (__low2float(v0) + __low2float(v1)) + (__low2float(v2) + __low2float(v3));
        a1 += (__high2float(v0) + __high2float(v1)) + (__high2float(v2) + __high2float(v3));
    }
    for (; e < d; e++) {
        __half2 v = z1p[(size_t)csr[beg + e] * 8 + c2];
        a0 += __low2float(v);
        a1 += __high2float(v);
    }
    float di = dinv[node];
    int cA = c2 * 2, cB = c2 * 2 + 1;
    float hA = fmaxf(fmaf(di, a0, b1[cA]), 0.f);
    float hB = fmaxf(fmaf(di, a1, b1[cB]), 0.f);
    float p0 = hA * W2[cA * 2 + 0] + hB * W2[cB * 2 + 0];
    float p1 = hA * W2[cA * 2 + 1] + hB * W2[cB * 2 + 1];
#pragma unroll
    for (int m = 1; m < 8; m <<= 1) {
        p0 += __shfl_xor(p0, m, 8);
        p1 += __shfl_xor(p1, m, 8);
    }
    if (c2 == 0) z2h[node] = __floats2half2_rn(di * p0, di * p1);
}

// --- gather layer 2: 8 lanes/node + bias + log_softmax(2) --------------------
__global__ void k_gather2(const int* __restrict__ ptr, const int* __restrict__ cnt,
                          const int* __restrict__ csr, const __half2* __restrict__ z2h,
                          const float* __restrict__ dinv,
                          const float* __restrict__ b2, float* __restrict__ out, int n) {
    int g = threadIdx.x >> 3;
    int c = threadIdx.x & 7;
    int node = blockIdx.x * 32 + g;
    if (node >= n) return;
    int beg = ptr[node], d = cnt[node];
    float a0 = 0.f, a1 = 0.f;
    for (int e = c; e < d; e += 8) {
        __half2 v = z2h[csr[beg + e]];
        a0 += __low2float(v);
        a1 += __high2float(v);
    }
#pragma unroll
    for (int m = 1; m < 8; m <<= 1) {
        a0 += __shfl_xor(a0, m, 8);
        a1 += __shfl_xor(a1, m, 8);
    }
    if (c == 0) {
        __half2 self = z2h[node];
        a0 += __low2float(self);
        a1 += __high2float(self);
        float di = dinv[node];
        float h0 = fmaf(di, a0, b2[0]);
        float h1 = fmaf(di, a1, b2[1]);
        float mx = fmaxf(h0, h1);
        float lse = mx + log1pf(expf(fminf(h0, h1) - mx));
        ((float2*)out)[node] = make_float2(h0 - lse, h1 - lse);
    }
}

// ===================== fallback: round-2 CSR pipeline ========================

__global__ void k_zero(int* cnt, int n) {
    int i = blockIdx.x * blockDim.x + threadIdx.x;
    if (i < n) cnt[i] = 0;
}

__global__ void k_count_pos(const int* __restrict__ col, int e,
                            int* __restrict__ cnt, int* __restrict__ pos) {
    int i = blockIdx.x * blockDim.x + threadIdx.x;
    if (i < e) pos[i] = atomicAdd(&cnt[col[i]], 1);
}

__global__ void k_scan1(const int* __restrict__ cnt, int n,
                        int* __restrict__ excl, int* __restrict__ bsum) {
    __shared__ int s[256];
    int i = blockIdx.x * 256 + threadIdx.x;
    int v = (i < n) ? cnt[i] : 0;
    s[threadIdx.x] = v;
    __syncthreads();
    for (int off = 1; off < 256; off <<= 1) {
        int t = (threadIdx.x >= off) ? s[threadIdx.x - off] : 0;
        __syncthreads();
        s[threadIdx.x] += t;
        __syncthreads();
    }
    if (i < n) excl[i] = s[threadIdx.x] - v;
    if (threadIdx.x == 255) bsum[blockIdx.x] = s[255];
}

__global__ void k_scan2(int* __restrict__ bsum, int nb) {
    __shared__ int s[1024];
    int v = (threadIdx.x < nb) ? bsum[threadIdx.x] : 0;
    s[threadIdx.x] = v;
    __syncthreads();
    for (int off = 1; off < 1024; off <<= 1) {
        int t = (threadIdx.x >= off) ? s[threadIdx.x - off] : 0;
        __syncthreads();
        s[threadIdx.x] += t;
        __syncthreads();
    }
    if (threadIdx.x < nb) bsum[threadIdx.x] = s[threadIdx.x] - v;
}

__global__ void k_scan3(int* __restrict__ excl, const int* __restrict__ boff, int n) {
    int i = blockIdx.x * 256 + threadIdx.x;
    if (i < n) excl[i] += boff[blockIdx.x];
}

__global__ void k_place(const int* __restrict__ row, const int* __restrict__ col,
                        const int* __restrict__ pos, const int* __restrict__ ptr,
                        int e, int* __restrict__ csr) {
    int i = blockIdx.x * blockDim.x + threadIdx.x;
    if (i >= e) return;
    csr[ptr[col[i]] + pos[i]] = row[i];
}

__global__ void k_dinv_from_cnt(const int* __restrict__ cnt, float* __restrict__ dinv, int n) {
    int i = blockIdx.x * blockDim.x + threadIdx.x;
    if (i < n) dinv[i] = rsqrtf((float)(cnt[i] + 1));
}

__global__ void k_gather1_fb(const int* __restrict__ ptr, const int* __restrict__ cnt,
                             const int* __restrict__ csr, const __half* __restrict__ z1h,
                             const float* __restrict__ dinv,
                             const float* __restrict__ b1, const float* __restrict__ W2,
                             __half2* __restrict__ z2h, int n) {
    int g = threadIdx.x >> 3;
    int c2 = threadIdx.x & 7;
    int node = blockIdx.x * 32 + g;
    if (node >= n) return;
    const __half2* z1p = (const __half2*)z1h;
    int beg = ptr[node], d = cnt[node];
    __half2 sv = z1p[(size_t)node * 8 + c2];
    float a0 = __low2float(sv), a1 = __high2float(sv);
    for (int e = 0; e < d; e++) {
        __half2 v = z1p[(size_t)csr[beg + e] * 8 + c2];
        a0 += __low2float(v);
        a1 += __high2float(v);
    }
    float di = dinv[node];
    int cA = c2 * 2, cB = c2 * 2 + 1;
    float hA = fmaxf(fmaf(di, a0, b1[cA]), 0.f);
    float hB = fmaxf(fmaf(di, a1, b1[cB]), 0.f);
    float p0 = hA * W2[cA * 2 + 0] + hB * W2[cB * 2 + 0];
    float p1 = hA * W2[cA * 2 + 1] + hB * W2[cB * 2 + 1];
#pragma unroll
    for (int m = 1; m < 8; m <<= 1) {
        p0 += __shfl_xor(p0, m, 8);
        p1 += __shfl_xor(p1, m, 8);
    }
    if (c2 == 0) z2h[node] = __floats2half2_rn(di * p0, di * p1);
}

// ============================== host launcher ================================

extern "C" void kernel_launch(void* const* d_in, const int* in_sizes, int n_in,
                              void* d_out, int out_size, void* d_ws, size_t ws_size,
                              hipStream_t stream) {
    const float* x  = (const float*)d_in[0];
    const int*   ei = (const int*)d_in[1];
    const float* W1 = (const float*)d_in[2];
    const float* b1 = (const float*)d_in[3];
    const float* W2 = (const float*)d_in[4];
    const float* b2 = (const float*)d_in[5];
    float* out = (float*)d_out;

    const int N = in_sizes[0] / 25;
    const int E = in_sizes[1] / 2;
    const int* row = ei;
    const int* col = ei + E;

    const int nbins = (N + NPB - 1) / NPB;
    const int gN = (N + THREADS - 1) / THREADS;
    const int gE = (E + THREADS - 1) / THREADS;

    size_t off = 0;
    auto take = [&](size_t bytes) { size_t o = off; off = (off + bytes + 255) & ~(size_t)255; return o; };
    size_t o_binCnt = take(MAX_BINS * sizeof(int));
    size_t o_binned = take((size_t)nbins * CAPE * sizeof(int));
    size_t o_csr    = take((size_t)nbins * CAPE * sizeof(int));
    size_t o_ptr    = take((size_t)N * sizeof(int));
    size_t o_cnt    = take((size_t)N * sizeof(int));
    size_t o_dinv   = take((size_t)N * sizeof(float));
    size_t o_z1h    = take((size_t)N * 16 * sizeof(__half));
    size_t o_z2h    = take((size_t)N * sizeof(__half2));
    size_t need_v17 = off;

    // bin load: mu + 8*sigma + 3*NPB pad (covers both x4 reservation pad and
    // csr alignment pad, each bounded by 3*BIN_BLOCKS=1536=3*NPB)
    double mu = (double)E / (double)nbins;
    bool cap_ok = (mu + 8.0 * sqrt(mu) + 3.0 * NPB) < (double)CAPE;
    const int per = (((E + BIN_BLOCKS - 1) / BIN_BLOCKS) + 3) & ~3;
    size_t dynLds = (size_t)per * 4 + 64;  // R19: sbuf2 only (4B/edge)
    bool lds_ok = dynLds <= 60 * 1024;
    bool use_v17 = (nbins <= MAX_BINS) && (ws_size >= need_v17) &&
                   (N <= NPB * MAX_BINS) && cap_ok && lds_ok &&
                   (3 * BIN_BLOCKS <= 3 * NPB);

    char* wsb = (char*)d_ws;
    if (use_v17) {
        int*     binCnt = (int*)(wsb + o_binCnt);
        int*     binned = (int*)(wsb + o_binned);
        int*     csr    = (int*)(wsb + o_csr);
        int*     ptr    = (int*)(wsb + o_ptr);
        int*     cnt    = (int*)(wsb + o_cnt);
        float*   dinv   = (float*)(wsb + o_dinv);
        __half*  z1h    = (__half*)(wsb + o_z1h);
        __half2* z2h    = (__half2*)(wsb + o_z2h);

        hipMemsetAsync(binCnt, 0, MAX_BINS * sizeof(int), stream);
        k_bin<<<BIN_BLOCKS, 512, dynLds, stream>>>(row, col, E, binCnt, binned);
        k_sort<<<nbins, 1024, 0, stream>>>(binned, binCnt, csr, ptr, cnt, dinv, x, W1, z1h, N);
        k_gather1<<<(N + 31) / 32, 256, 0, stream>>>(ptr, cnt, csr, z1h, dinv, b1, W2, z2h, N);
        k_gather2<<<(N + 31) / 32, 256, 0, stream>>>(ptr, cnt, csr, z2h, dinv, b2, out, N);
    } else {
        char* w = wsb;
        int*     cnt  = (int*)w;     w += (size_t)N * sizeof(int);
        int*     ptr  = (int*)w;     w += (size_t)N * sizeof(int);
        int*     pos  = (int*)w;     w += (size_t)E * sizeof(int);
        int*     csr  = (int*)w;     w += (size_t)E * sizeof(int);
        int*     bsum = (int*)w;     w += (size_t)1024 * sizeof(int);
        float*   dinv = (float*)w;   w += (size_t)N * sizeof(float);
        __half*  z1h  = (__half*)w;  w += (size_t)N * 16 * sizeof(__half);
        __half2* z2h  = (__half2*)w; w += (size_t)N * sizeof(__half2);
        const int NB = (N + 255) / 256;

        k_zero<<<gN, THREADS, 0, stream>>>(cnt, N);
        k_count_pos<<<gE, THREADS, 0, stream>>>(col, E, cnt, pos);
        k_scan1<<<NB, 256, 0, stream>>>(cnt, N, ptr, bsum);
        k_scan2<<<1, 1024, 0, stream>>>(bsum, NB);
        k_scan3<<<NB, 256, 0, stream>>>(ptr, bsum, N);
        k_place<<<gE, THREADS, 0, stream>>>(row, col, pos, ptr, E, csr);
        k_dinv_from_cnt<<<gN, THREADS, 0, stream>>>(cnt, dinv, N);
        k_xform1<<<gN, 256, 0, stream>>>(x, W1, dinv, z1h, N);
        k_gather1_fb<<<(N + 31) / 32, 256, 0, stream>>>(ptr, cnt, csr, z1h, dinv, b1, W2, z2h, N);
        k_gather2<<<(N + 31) / 32, 256, 0, stream>>>(ptr, cnt, csr, z2h, dinv, b2, out, N);
    }
}

// Round 8
// 175.499 us; speedup vs baseline: 4.2850x; 1.0231x over previous
//
#include <hip/hip_runtime.h>
#include <hip/hip_fp16.h>
#include <math.h>

#define THREADS 256
#define NPB 512           // nodes per bin
#define SHIFT 9
#define MASK 511
#define MAX_BINS 256
#define CAPE 20480        // per-bin capacity (true mean 16384, +8 sigma, +3*512 pad)
#define BIN_BLOCKS 512
#define SENT (-1)         // sentinel for pad slots (valid packed edges < 2^31)

// ===================== stage 1: bin edges by target>>9 =======================
// R17: reservations padded to x4; pass C flushes int4 chunks, SENT pads.
// R19: no sbuf/sbin staging; pass A histograms col; pass B re-reads row/col.
// R26: unchanged (R18/R19 A/B showed bin/sort are not the lever).

__global__ void __launch_bounds__(512) k_bin(const int* __restrict__ row,
                                             const int* __restrict__ col,
                                             int e, int* __restrict__ binCnt,
                                             int* __restrict__ binned) {
    __shared__ int hist[MAX_BINS];
    __shared__ int cur[MAX_BINS];
    __shared__ int baseg[MAX_BINS];
    __shared__ int lofs[MAX_BINS];
    __shared__ int scn[MAX_BINS];
    extern __shared__ int sbuf2[];   // per ints
    int per = (((e + (int)gridDim.x - 1) / (int)gridDim.x) + 3) & ~3;
    int e0 = blockIdx.x * per;
    if (e0 >= e) return;
    int e1 = min(e0 + per, e);
    int cntL = e1 - e0;
    int tid = threadIdx.x;
    if (tid < MAX_BINS) { hist[tid] = 0; cur[tid] = 0; }
    __syncthreads();
    int nq = cntL >> 2;
    const int4* r4 = (const int4*)(row + e0);
    const int4* c4 = (const int4*)(col + e0);
    // pass A: histogram only (col read, 4 LDS atomics per int4)
    for (int q = tid; q < nq; q += 512) {
        int4 c = c4[q];
        atomicAdd(&hist[c.x >> SHIFT], 1);
        atomicAdd(&hist[c.y >> SHIFT], 1);
        atomicAdd(&hist[c.z >> SHIFT], 1);
        atomicAdd(&hist[c.w >> SHIFT], 1);
    }
    for (int li = (nq << 2) + tid; li < cntL; li += 512) {
        atomicAdd(&hist[col[e0 + li] >> SHIFT], 1);
    }
    __syncthreads();
    if (tid < MAX_BINS) {
        int h = hist[tid];
        baseg[tid] = (h > 0) ? atomicAdd(&binCnt[tid], (h + 3) & ~3) : 0;  // x4 pad
        scn[tid] = h;
    }
    __syncthreads();
    for (int off = 1; off < MAX_BINS; off <<= 1) {
        int a = (tid >= off && tid < MAX_BINS) ? scn[tid - off] : 0;
        __syncthreads();
        if (tid < MAX_BINS) scn[tid] += a;
        __syncthreads();
    }
    if (tid < MAX_BINS) lofs[tid] = scn[tid] - hist[tid];
    __syncthreads();
    // pass B: re-read row+col, pack, scatter bin-contiguous into sbuf2
    for (int q = tid; q < nq; q += 512) {
        int4 r = r4[q], c = c4[q];
        int b0 = c.x >> SHIFT, b1 = c.y >> SHIFT, b2 = c.z >> SHIFT, b3 = c.w >> SHIFT;
        int p0 = lofs[b0] + atomicAdd(&cur[b0], 1);
        sbuf2[p0] = (r.x << SHIFT) | (c.x & MASK);
        int p1 = lofs[b1] + atomicAdd(&cur[b1], 1);
        sbuf2[p1] = (r.y << SHIFT) | (c.y & MASK);
        int p2 = lofs[b2] + atomicAdd(&cur[b2], 1);
        sbuf2[p2] = (r.z << SHIFT) | (c.z & MASK);
        int p3 = lofs[b3] + atomicAdd(&cur[b3], 1);
        sbuf2[p3] = (r.w << SHIFT) | (c.w & MASK);
    }
    for (int li = (nq << 2) + tid; li < cntL; li += 512) {
        int c = col[e0 + li], r = row[e0 + li], b = c >> SHIFT;
        int p = lofs[b] + atomicAdd(&cur[b], 1);
        sbuf2[p] = (r << SHIFT) | (c & MASK);
    }
    __syncthreads();
    // pass C: wave-per-bin flush, int4 chunks (baseg multiple of 4)
    int wv = tid >> 6, ln = tid & 63;
    for (int b = wv; b < MAX_BINS; b += 8) {
        int len = hist[b];
        if (len == 0) continue;
        int lo = lofs[b];
        int gb = baseg[b];
        int n4 = (len + 3) >> 2;
        for (int i4 = ln; i4 < n4; i4 += 64) {
            int base = i4 * 4;
            int4 v;
            v.x = (base + 0 < len) ? sbuf2[lo + base + 0] : SENT;
            v.y = (base + 1 < len) ? sbuf2[lo + base + 1] : SENT;
            v.z = (base + 2 < len) ? sbuf2[lo + base + 2] : SENT;
            v.w = (base + 3 < len) ? sbuf2[lo + base + 3] : SENT;
            int pos = gb + base;
            if (pos + 4 <= CAPE) *(int4*)(binned + b * CAPE + pos) = v;
        }
    }
}

// ======= stage 2 (FUSED): per-bin counting sort -> CSR + deg + dinv ==========
// + layer-1 transform. R19: binned read ONCE into 5 statically-indexed int4
// registers; histogram + placement run from registers. Unchanged in R26.

__global__ void __launch_bounds__(1024) k_sort(const int* __restrict__ binned,
                                               const int* __restrict__ binCnt,
                                               int* __restrict__ csr,
                                               int* __restrict__ gptr,
                                               int* __restrict__ gcnt,
                                               float* __restrict__ dinv,
                                               const float* __restrict__ x,
                                               const float* __restrict__ W1,
                                               __half* __restrict__ z1h, int n) {
    __shared__ int cnt[NPB];
    __shared__ int scn[NPB];
    __shared__ float sW[25 * 16];
    int b = blockIdx.x;
    int t = threadIdx.x;
    if (t < NPB) cnt[t] = 0;
    if (t < 25 * 16) sW[t] = W1[t];
    __syncthreads();
    int m = min(binCnt[b], CAPE);   // multiple of 4 (padded reservations)
    int m4 = m >> 2;
    const int4* eb4 = (const int4*)(binned + b * CAPE);
    const int4 S4 = make_int4(SENT, SENT, SENT, SENT);
    int4 q0 = (t          < m4) ? eb4[t]          : S4;
    int4 q1 = (t + 1024   < m4) ? eb4[t + 1024]   : S4;
    int4 q2 = (t + 2048   < m4) ? eb4[t + 2048]   : S4;
    int4 q3 = (t + 3072   < m4) ? eb4[t + 3072]   : S4;
    int4 q4 = (t + 4096   < m4) ? eb4[t + 4096]   : S4;
#define H4(q) { \
    if (q.x != SENT) atomicAdd(&cnt[q.x & MASK], 1); \
    if (q.y != SENT) atomicAdd(&cnt[q.y & MASK], 1); \
    if (q.z != SENT) atomicAdd(&cnt[q.z & MASK], 1); \
    if (q.w != SENT) atomicAdd(&cnt[q.w & MASK], 1); }
    H4(q0) H4(q1) H4(q2) H4(q3) H4(q4)
#undef H4
    __syncthreads();
    int v = 0, pv = 0;
    if (t < NPB) {
        v = cnt[t];
        pv = (v + 3) & ~3;  // 4-aligned degree for csr segment alignment
        scn[t] = pv;
    }
    __syncthreads();
    for (int off = 1; off < NPB; off <<= 1) {
        int a = (t >= off && t < NPB) ? scn[t - off] : 0;
        __syncthreads();
        if (t < NPB) scn[t] += a;
        __syncthreads();
    }
    int node = b * NPB + t;
    float di = rsqrtf((float)(v + 1));
    if (t < NPB) {
        int excl = scn[t] - pv;  // multiple of 4
        if (node < n) {
            gptr[node] = b * CAPE + excl;
            gcnt[node] = v;
            dinv[node] = di;
        }
        cnt[t] = excl;  // reuse as cursor
    }
    __syncthreads();
#define P4(q) { \
    int e, slot; \
    e = q.x; if (e != SENT) { slot = atomicAdd(&cnt[e & MASK], 1); if (slot < CAPE) csr[b * CAPE + slot] = e >> SHIFT; } \
    e = q.y; if (e != SENT) { slot = atomicAdd(&cnt[e & MASK], 1); if (slot < CAPE) csr[b * CAPE + slot] = e >> SHIFT; } \
    e = q.z; if (e != SENT) { slot = atomicAdd(&cnt[e & MASK], 1); if (slot < CAPE) csr[b * CAPE + slot] = e >> SHIFT; } \
    e = q.w; if (e != SENT) { slot = atomicAdd(&cnt[e & MASK], 1); if (slot < CAPE) csr[b * CAPE + slot] = e >> SHIFT; } }
    P4(q0) P4(q1) P4(q2) P4(q3) P4(q4)
#undef P4
    // fused layer-1 transform for this bin's nodes
    if (t < NPB && node < n) {
        const float* xr = x + (size_t)node * 25;
        float xi[25];
#pragma unroll
        for (int k = 0; k < 25; k++) xi[k] = xr[k];
        union { int4 q[2]; __half h[16]; } u;
#pragma unroll
        for (int c = 0; c < 16; c++) {
            float a = 0.f;
#pragma unroll
            for (int k = 0; k < 25; k++) a = fmaf(xi[k], sW[k * 16 + c], a);
            u.h[c] = __float2half(a * di);
        }
        int4* o = (int4*)(z1h + (size_t)node * 16);
        o[0] = u.q[0];
        o[1] = u.q[1];
    }
}

// --- standalone xform1 (fallback path only) ----------------------------------
__global__ void __launch_bounds__(256) k_xform1(const float* __restrict__ x,
                                                const float* __restrict__ W1,
                                                const float* __restrict__ dinv,
                                                __half* __restrict__ z1h, int n) {
    __shared__ float sW[25 * 16];
    for (int t = threadIdx.x; t < 25 * 16; t += 256) sW[t] = W1[t];
    __syncthreads();
    long node = (long)blockIdx.x * 256 + threadIdx.x;
    if (node >= n) return;
    const float* xr = x + node * 25;
    float xi[25];
#pragma unroll
    for (int k = 0; k < 25; k++) xi[k] = xr[k];
    float di = dinv[node];
    union { int4 q[2]; __half h[16]; } u;
#pragma unroll
    for (int c = 0; c < 16; c++) {
        float a = 0.f;
#pragma unroll
        for (int k = 0; k < 25; k++) a = fmaf(xi[k], sW[k * 16 + c], a);
        u.h[c] = __float2half(a * di);
    }
    int4* o = (int4*)(z1h + node * 16);
    o[0] = u.q[0];
    o[1] = u.q[1];
}

// --- gather layer 1 + bias/relu + @W2: 8 lanes/node, half2 loads -------------
// R26: e-loop unrolled to 8 edges/iter (2 independent csr int4 + 8 independent
// z1h loads in flight). Gathers are L3-latency/concurrency-bound (z1h evicted
// from L2 by csr streaming); doubling MLP per wave is the matching lever.
__global__ void k_gather1(const int* __restrict__ ptr, const int* __restrict__ cnt,
                          const int* __restrict__ csr, const __half* __restrict__ z1h,
                          const float* __restrict__ dinv,
                          const float* __restrict__ b1, const float* __restrict__ W2,
                          __half2* __restrict__ z2h, int n) {
    int g = threadIdx.x >> 3;
    int c2 = threadIdx.x & 7;
    int node = blockIdx.x * 32 + g;
    if (node >= n) return;
    const __half2* z1p = (const __half2*)z1h;
    int beg = ptr[node], d = cnt[node];
    __half2 sv = z1p[(size_t)node * 8 + c2];
    float a0 = __low2float(sv), a1 = __high2float(sv);
    int e = 0;
    for (; e + 8 <= d; e += 8) {
        int4 s0 = *(const int4*)(csr + beg + e);      // aligned: beg%4==0
        int4 s1 = *(const int4*)(csr + beg + e + 4);
        __half2 v0 = z1p[(size_t)s0.x * 8 + c2];
        __half2 v1 = z1p[(size_t)s0.y * 8 + c2];
        __half2 v2 = z1p[(size_t)s0.z * 8 + c2];
        __half2 v3 = z1p[(size_t)s0.w * 8 + c2];
        __half2 v4 = z1p[(size_t)s1.x * 8 + c2];
        __half2 v5 = z1p[(size_t)s1.y * 8 + c2];
        __half2 v6 = z1p[(size_t)s1.z * 8 + c2];
        __half2 v7 = z1p[(size_t)s1.w * 8 + c2];
        a0 += ((__low2float(v0) + __low2float(v1)) + (__low2float(v2) + __low2float(v3))) +
              ((__low2float(v4) + __low2float(v5)) + (__low2float(v6) + __low2float(v7)));
        a1 += ((__high2float(v0) + __high2float(v1)) + (__high2float(v2) + __high2float(v3))) +
              ((__high2float(v4) + __high2float(v5)) + (__high2float(v6) + __high2float(v7)));
    }
    for (; e + 4 <= d; e += 4) {
        int4 s = *(const int4*)(csr + beg + e);
        __half2 v0 = z1p[(size_t)s.x * 8 + c2];
        __half2 v1 = z1p[(size_t)s.y * 8 + c2];
        __half2 v2 = z1p[(size_t)s.z * 8 + c2];
        __half2 v3 = z1p[(size_t)s.w * 8 + c2];
        a0 += (__low2float(v0) + __low2float(v1)) + (__low2float(v2) + __low2float(v3));
        a1 += (__high2float(v0) + __high2float(v1)) + (__high2float(v2) + __high2float(v3));
    }
    for (; e < d; e++) {
        __half2 v = z1p[(size_t)csr[beg + e] * 8 + c2];
        a0 += __low2float(v);
        a1 += __high2float(v);
    }
    float di = dinv[node];
    int cA = c2 * 2, cB = c2 * 2 + 1;
    float hA = fmaxf(fmaf(di, a0, b1[cA]), 0.f);
    float hB = fmaxf(fmaf(di, a1, b1[cB]), 0.f);
    float p0 = hA * W2[cA * 2 + 0] + hB * W2[cB * 2 + 0];
    float p1 = hA * W2[cA * 2 + 1] + hB * W2[cB * 2 + 1];
#pragma unroll
    for (int m = 1; m < 8; m <<= 1) {
        p0 += __shfl_xor(p0, m, 8);
        p1 += __shfl_xor(p1, m, 8);
    }
    if (c2 == 0) z2h[node] = __floats2half2_rn(di * p0, di * p1);
}

// --- gather layer 2: 8 lanes/node + bias + log_softmax(2) --------------------
// R26: 2 edges/lane/iteration (independent loads) for 2x MLP.
__global__ void k_gather2(const int* __restrict__ ptr, const int* __restrict__ cnt,
                          const int* __restrict__ csr, const __half2* __restrict__ z2h,
                          const float* __restrict__ dinv,
                          const float* __restrict__ b2, float* __restrict__ out, int n) {
    int g = threadIdx.x >> 3;
    int c = threadIdx.x & 7;
    int node = blockIdx.x * 32 + g;
    if (node >= n) return;
    int beg = ptr[node], d = cnt[node];
    float a0 = 0.f, a1 = 0.f;
    int e = c;
    for (; e + 8 < d; e += 16) {
        int i0 = csr[beg + e];
        int i1 = csr[beg + e + 8];
        __half2 w0 = z2h[i0];
        __half2 w1 = z2h[i1];
        a0 += __low2float(w0) + __low2float(w1);
        a1 += __high2float(w0) + __high2float(w1);
    }
    for (; e < d; e += 8) {
        __half2 v = z2h[csr[beg + e]];
        a0 += __low2float(v);
        a1 += __high2float(v);
    }
#pragma unroll
    for (int m = 1; m < 8; m <<= 1) {
        a0 += __shfl_xor(a0, m, 8);
        a1 += __shfl_xor(a1, m, 8);
    }
    if (c == 0) {
        __half2 self = z2h[node];
        a0 += __low2float(self);
        a1 += __high2float(self);
        float di = dinv[node];
        float h0 = fmaf(di, a0, b2[0]);
        float h1 = fmaf(di, a1, b2[1]);
        float mx = fmaxf(h0, h1);
        float lse = mx + log1pf(expf(fminf(h0, h1) - mx));
        ((float2*)out)[node] = make_float2(h0 - lse, h1 - lse);
    }
}

// ===================== fallback: round-2 CSR pipeline ========================

__global__ void k_zero(int* cnt, int n) {
    int i = blockIdx.x * blockDim.x + threadIdx.x;
    if (i < n) cnt[i] = 0;
}

__global__ void k_count_pos(const int* __restrict__ col, int e,
                            int* __restrict__ cnt, int* __restrict__ pos) {
    int i = blockIdx.x * blockDim.x + threadIdx.x;
    if (i < e) pos[i] = atomicAdd(&cnt[col[i]], 1);
}

__global__ void k_scan1(const int* __restrict__ cnt, int n,
                        int* __restrict__ excl, int* __restrict__ bsum) {
    __shared__ int s[256];
    int i = blockIdx.x * 256 + threadIdx.x;
    int v = (i < n) ? cnt[i] : 0;
    s[threadIdx.x] = v;
    __syncthreads();
    for (int off = 1; off < 256; off <<= 1) {
        int t = (threadIdx.x >= off) ? s[threadIdx.x - off] : 0;
        __syncthreads();
        s[threadIdx.x] += t;
        __syncthreads();
    }
    if (i < n) excl[i] = s[threadIdx.x] - v;
    if (threadIdx.x == 255) bsum[blockIdx.x] = s[255];
}

__global__ void k_scan2(int* __restrict__ bsum, int nb) {
    __shared__ int s[1024];
    int v = (threadIdx.x < nb) ? bsum[threadIdx.x] : 0;
    s[threadIdx.x] = v;
    __syncthreads();
    for (int off = 1; off < 1024; off <<= 1) {
        int t = (threadIdx.x >= off) ? s[threadIdx.x - off] : 0;
        __syncthreads();
        s[threadIdx.x] += t;
        __syncthreads();
    }
    if (threadIdx.x < nb) bsum[threadIdx.x] = s[threadIdx.x] - v;
}

__global__ void k_scan3(int* __restrict__ excl, const int* __restrict__ boff, int n) {
    int i = blockIdx.x * 256 + threadIdx.x;
    if (i < n) excl[i] += boff[blockIdx.x];
}

__global__ void k_place(const int* __restrict__ row, const int* __restrict__ col,
                        const int* __restrict__ pos, const int* __restrict__ ptr,
                        int e, int* __restrict__ csr) {
    int i = blockIdx.x * blockDim.x + threadIdx.x;
    if (i >= e) return;
    csr[ptr[col[i]] + pos[i]] = row[i];
}

__global__ void k_dinv_from_cnt(const int* __restrict__ cnt, float* __restrict__ dinv, int n) {
    int i = blockIdx.x * blockDim.x + threadIdx.x;
    if (i < n) dinv[i] = rsqrtf((float)(cnt[i] + 1));
}

__global__ void k_gather1_fb(const int* __restrict__ ptr, const int* __restrict__ cnt,
                             const int* __restrict__ csr, const __half* __restrict__ z1h,
                             const float* __restrict__ dinv,
                             const float* __restrict__ b1, const float* __restrict__ W2,
                             __half2* __restrict__ z2h, int n) {
    int g = threadIdx.x >> 3;
    int c2 = threadIdx.x & 7;
    int node = blockIdx.x * 32 + g;
    if (node >= n) return;
    const __half2* z1p = (const __half2*)z1h;
    int beg = ptr[node], d = cnt[node];
    __half2 sv = z1p[(size_t)node * 8 + c2];
    float a0 = __low2float(sv), a1 = __high2float(sv);
    for (int e = 0; e < d; e++) {
        __half2 v = z1p[(size_t)csr[beg + e] * 8 + c2];
        a0 += __low2float(v);
        a1 += __high2float(v);
    }
    float di = dinv[node];
    int cA = c2 * 2, cB = c2 * 2 + 1;
    float hA = fmaxf(fmaf(di, a0, b1[cA]), 0.f);
    float hB = fmaxf(fmaf(di, a1, b1[cB]), 0.f);
    float p0 = hA * W2[cA * 2 + 0] + hB * W2[cB * 2 + 0];
    float p1 = hA * W2[cA * 2 + 1] + hB * W2[cB * 2 + 1];
#pragma unroll
    for (int m = 1; m < 8; m <<= 1) {
        p0 += __shfl_xor(p0, m, 8);
        p1 += __shfl_xor(p1, m, 8);
    }
    if (c2 == 0) z2h[node] = __floats2half2_rn(di * p0, di * p1);
}

// ============================== host launcher ================================

extern "C" void kernel_launch(void* const* d_in, const int* in_sizes, int n_in,
                              void* d_out, int out_size, void* d_ws, size_t ws_size,
                              hipStream_t stream) {
    const float* x  = (const float*)d_in[0];
    const int*   ei = (const int*)d_in[1];
    const float* W1 = (const float*)d_in[2];
    const float* b1 = (const float*)d_in[3];
    const float* W2 = (const float*)d_in[4];
    const float* b2 = (const float*)d_in[5];
    float* out = (float*)d_out;

    const int N = in_sizes[0] / 25;
    const int E = in_sizes[1] / 2;
    const int* row = ei;
    const int* col = ei + E;

    const int nbins = (N + NPB - 1) / NPB;
    const int gN = (N + THREADS - 1) / THREADS;
    const int gE = (E + THREADS - 1) / THREADS;

    size_t off = 0;
    auto take = [&](size_t bytes) { size_t o = off; off = (off + bytes + 255) & ~(size_t)255; return o; };
    size_t o_binCnt = take(MAX_BINS * sizeof(int));
    size_t o_binned = take((size_t)nbins * CAPE * sizeof(int));
    size_t o_csr    = take((size_t)nbins * CAPE * sizeof(int));
    size_t o_ptr    = take((size_t)N * sizeof(int));
    size_t o_cnt    = take((size_t)N * sizeof(int));
    size_t o_dinv   = take((size_t)N * sizeof(float));
    size_t o_z1h    = take((size_t)N * 16 * sizeof(__half));
    size_t o_z2h    = take((size_t)N * sizeof(__half2));
    size_t need_v17 = off;

    // bin load: mu + 8*sigma + 3*NPB pad (covers both x4 reservation pad and
    // csr alignment pad, each bounded by 3*BIN_BLOCKS=1536=3*NPB)
    double mu = (double)E / (double)nbins;
    bool cap_ok = (mu + 8.0 * sqrt(mu) + 3.0 * NPB) < (double)CAPE;
    const int per = (((E + BIN_BLOCKS - 1) / BIN_BLOCKS) + 3) & ~3;
    size_t dynLds = (size_t)per * 4 + 64;  // sbuf2 only (4B/edge)
    bool lds_ok = dynLds <= 60 * 1024;
    bool use_v17 = (nbins <= MAX_BINS) && (ws_size >= need_v17) &&
                   (N <= NPB * MAX_BINS) && cap_ok && lds_ok &&
                   (3 * BIN_BLOCKS <= 3 * NPB);

    char* wsb = (char*)d_ws;
    if (use_v17) {
        int*     binCnt = (int*)(wsb + o_binCnt);
        int*     binned = (int*)(wsb + o_binned);
        int*     csr    = (int*)(wsb + o_csr);
        int*     ptr    = (int*)(wsb + o_ptr);
        int*     cnt    = (int*)(wsb + o_cnt);
        float*   dinv   = (float*)(wsb + o_dinv);
        __half*  z1h    = (__half*)(wsb + o_z1h);
        __half2* z2h    = (__half2*)(wsb + o_z2h);

        hipMemsetAsync(binCnt, 0, MAX_BINS * sizeof(int), stream);
        k_bin<<<BIN_BLOCKS, 512, dynLds, stream>>>(row, col, E, binCnt, binned);
        k_sort<<<nbins, 1024, 0, stream>>>(binned, binCnt, csr, ptr, cnt, dinv, x, W1, z1h, N);
        k_gather1<<<(N + 31) / 32, 256, 0, stream>>>(ptr, cnt, csr, z1h, dinv, b1, W2, z2h, N);
        k_gather2<<<(N + 31) / 32, 256, 0, stream>>>(ptr, cnt, csr, z2h, dinv, b2, out, N);
    } else {
        char* w = wsb;
        int*     cnt  = (int*)w;     w += (size_t)N * sizeof(int);
        int*     ptr  = (int*)w;     w += (size_t)N * sizeof(int);
        int*     pos  = (int*)w;     w += (size_t)E * sizeof(int);
        int*     csr  = (int*)w;     w += (size_t)E * sizeof(int);
        int*     bsum = (int*)w;     w += (size_t)1024 * sizeof(int);
        float*   dinv = (float*)w;   w += (size_t)N * sizeof(float);
        __half*  z1h  = (__half*)w;  w += (size_t)N * 16 * sizeof(__half);
        __half2* z2h  = (__half2*)w; w += (size_t)N * sizeof(__half2);
        const int NB = (N + 255) / 256;

        k_zero<<<gN, THREADS, 0, stream>>>(cnt, N);
        k_count_pos<<<gE, THREADS, 0, stream>>>(col, E, cnt, pos);
        k_scan1<<<NB, 256, 0, stream>>>(cnt, N, ptr, bsum);
        k_scan2<<<1, 1024, 0, stream>>>(bsum, NB);
        k_scan3<<<NB, 256, 0, stream>>>(ptr, bsum, N);
        k_place<<<gE, THREADS, 0, stream>>>(row, col, pos, ptr, E, csr);
        k_dinv_from_cnt<<<gN, THREADS, 0, stream>>>(cnt, dinv, N);
        k_xform1<<<gN, 256, 0, stream>>>(x, W1, dinv, z1h, N);
        k_gather1_fb<<<(N + 31) / 32, 256, 0, stream>>>(ptr, cnt, csr, z1h, dinv, b1, W2, z2h, N);
        k_gather2<<<(N + 31) / 32, 256, 0, stream>>>(ptr, cnt, csr, z2h, dinv, b2, out, N);
    }
}